// Round 7
// baseline (326.076 us; speedup 1.0000x reference)
//
#include <hip/hip_runtime.h>
#include <stdint.h>

typedef unsigned short u16;
typedef __attribute__((ext_vector_type(8))) short bf16x8;
typedef __attribute__((ext_vector_type(4))) float f32x4;

#define DEV static __device__ __forceinline__

// problem dims
#define BB    2
#define CC    64
#define DDD   8
#define HHH   32
#define WWW   32
#define DHW   8192
#define MTOT  16384
#define GG    8
#define KTOT  1728
#define NOFF  1296
#define NOFFP 1408
#define COFF  648

// d_out element offsets (out, off1, off2 concatenated)
#define OFF1_ELEM (BB*CC*DHW)                 // 1048576
#define OFF2_ELEM (OFF1_ELEM + BB*COFF*DHW)   // 11665408

// ws byte offsets (all 256-aligned)
#define XCL_OFF   0ull         // bf16 [16384][64] channels-last x
#define YCL_OFF   2097152ull   // bf16 [16384][64] channels-last relu(bn1)
#define WOFF_OFF  4194304ull   // bf16 [1408][1728] off weights (k = tap*64+cin)
#define W1_OFF    9060352ull   // bf16 [64][1728]
#define W2_OFF    9281536ull
#define C1_OFF    9502720ull   // f32 [16384][64] deform1 raw out (channels-last)
#define C2_OFF    13697024ull
#define ST1_OFF   17891328ull  // f32 scale[64], shift[64]
#define ST2_OFF   17891840ull
#define ZPG_OFF   17892352ull  // 256B zeros (OOB source for global_load_lds)
#define PART_OFF  17892608ull  // f32 [1024][128] bn partials (from k_deform)

DEV float bf2f(u16 u){ union { uint32_t i; float f; } v; v.i = ((uint32_t)u) << 16; return v.f; }
DEV u16 f2bf(float f){ union { float f; uint32_t i; } v; v.f = f;
  uint32_t r = v.i + 0x7fffu + ((v.i >> 16) & 1u); return (u16)(r >> 16); }

DEV void gld16(const void* g, void* l){
  __builtin_amdgcn_global_load_lds((const __attribute__((address_space(1))) void*)g,
                                   (__attribute__((address_space(3))) void*)l, 16, 0, 0);
}

// ---------------- merged prep ----------------
#define PRE0 (BB*CC*DHW)            // xcl
#define PRE1 (PRE0 + NOFFP*KTOT)    // woff
#define PRE2 (PRE1 + CC*KTOT)       // w1b
#define PRE3 (PRE2 + CC*KTOT)       // w2b
#define PRETOT (PRE3 + 128)         // zpg (128 u16)

__global__ void k_prep(const float* __restrict__ x,
                       const float* __restrict__ wo1, const float* __restrict__ wo2,
                       const float* __restrict__ w1, const float* __restrict__ w2,
                       u16* __restrict__ xcl, u16* __restrict__ woff,
                       u16* __restrict__ w1b, u16* __restrict__ w2b,
                       u16* __restrict__ zpg)
{
  int idx = blockIdx.x * 256 + threadIdx.x;
  if (idx < PRE0) {
    int p = idx & (DHW - 1);
    int c = (idx >> 13) & 63;
    int b = idx >> 19;
    xcl[(size_t)(b * DHW + p) * CC + c] = f2bf(x[idx]);
  } else if (idx < PRE1) {
    int j = idx - PRE0;
    int k = j % KTOT, n = j / KTOT;
    int tap = k >> 6, cin = k & 63;
    float v = 0.f;
    if (n < NOFF) {
      const float* w = (n < COFF) ? wo1 : wo2;
      int nn = (n < COFF) ? n : n - COFF;
      v = w[(size_t)nn * KTOT + cin * 27 + tap];
    }
    woff[j] = f2bf(v);
  } else if (idx < PRE2) {
    int j = idx - PRE1;
    int k = j % KTOT, n = j / KTOT;
    int tap = k >> 6, cin = k & 63;
    w1b[j] = f2bf(w1[(size_t)n * KTOT + cin * 27 + tap]);
  } else if (idx < PRE3) {
    int j = idx - PRE2;
    int k = j % KTOT, n = j / KTOT;
    int tap = k >> 6, cin = k & 63;
    w2b[j] = f2bf(w2[(size_t)n * KTOT + cin * 27 + tap]);
  } else if (idx < PRETOT) {
    zpg[idx - PRE3] = 0;
  }
}

// ---------------- offset conv GEMM: counted-vmcnt 2-phase pipeline (T3/T4/T5) ----------------
// BM=BN=128, 256 threads, dbuf 64KB. Per tap: issue STAGE(t+1), ds_read+MFMA(t),
// vmcnt(0) AFTER MFMA (loads landed under compute), ONE raw barrier. sched_barrier
// pins (rule 18). LDS[row][chunk] = global[row][chunk ^ (row&7)] (chunk=16B).
__global__ __launch_bounds__(256) void k_gemm_off(
    const u16* __restrict__ xcl, const u16* __restrict__ woff,
    const float* __restrict__ boff1, const float* __restrict__ boff2,
    float* __restrict__ dout, const u16* __restrict__ zpg)
{
  __shared__ u16 Al[2 * 128 * 64];   // 32KB
  __shared__ u16 Bl[2 * 128 * 64];   // 32KB
  const int tid = threadIdx.x;
  const int wv = tid >> 6, lane = tid & 63;
  const int m0 = blockIdx.x * 128;
  const int n0 = blockIdx.y * 128;
  const int lr = lane >> 3, lc = lane & 7;
  const int lcs = (lc ^ lr) << 3;      // swizzled source element offset within 128B row
  const int b  = m0 >> 13;
  const int p0 = m0 & (DHW - 1);
  int ad[4], ah[4], aw[4];
  #pragma unroll
  for (int i = 0; i < 4; ++i) {
    int p = p0 + wv * 32 + i * 8 + lr;
    ad[i] = p >> 10; ah[i] = (p >> 5) & 31; aw[i] = p & 31;
  }
  const size_t xb = (size_t)b * DHW * CC;

  f32x4 acc[4][4] = {};
  const int wm = wv >> 1, wn = wv & 1;
  const int r16 = lane & 15, q = lane >> 4;
  const int rs = r16 & 7;

  auto stage = [&](int buf, int t) {
    int kd = t / 9 - 1, kh = (t / 3) % 3 - 1, kw = t % 3 - 1;
    u16* Ab = &Al[buf * 8192];
    u16* Bb = &Bl[buf * 8192];
    #pragma unroll
    for (int i = 0; i < 4; ++i) {
      int d2 = ad[i] + kd, h2 = ah[i] + kh, w2 = aw[i] + kw;
      bool ok = ((unsigned)d2 < DDD) & ((unsigned)h2 < HHH) & ((unsigned)w2 < WWW);
      const u16* src = ok ? (xcl + xb + (size_t)((d2 << 10) + (h2 << 5) + w2) * CC + lcs)
                          : zpg;
      gld16(src, &Ab[(wv * 32 + i * 8) * 64]);
    }
    #pragma unroll
    for (int i = 0; i < 4; ++i) {
      int r = wv * 32 + i * 8 + lr;
      const u16* src = woff + (size_t)(n0 + r) * KTOT + t * 64 + lcs;
      gld16(src, &Bb[(wv * 32 + i * 8) * 64]);
    }
  };

  // prologue: fill buf0, full drain, barrier
  stage(0, 0);
  asm volatile("s_waitcnt vmcnt(0)" ::: "memory");
  __builtin_amdgcn_sched_barrier(0);
  __builtin_amdgcn_s_barrier();
  __builtin_amdgcn_sched_barrier(0);

  int cur = 0;
  for (int t = 0; t < 27; ++t) {
    if (t < 26) stage(cur ^ 1, t + 1);     // next-tap loads in flight during MFMA
    const u16* Ab = &Al[cur * 8192];
    const u16* Bb = &Bl[cur * 8192];
    __builtin_amdgcn_s_setprio(1);
    #pragma unroll
    for (int kk = 0; kk < 2; ++kk) {
      const int cs = ((kk * 4 + q) ^ rs) << 3;   // swizzled read chunk
      bf16x8 af[4], bfr[4];
      #pragma unroll
      for (int i = 0; i < 4; ++i)
        af[i] = *(const bf16x8*)&Ab[(wm * 64 + i * 16 + r16) * 64 + cs];
      #pragma unroll
      for (int j = 0; j < 4; ++j)
        bfr[j] = *(const bf16x8*)&Bb[(wn * 64 + j * 16 + r16) * 64 + cs];
      #pragma unroll
      for (int i = 0; i < 4; ++i)
        #pragma unroll
        for (int j = 0; j < 4; ++j)
          acc[i][j] = __builtin_amdgcn_mfma_f32_16x16x32_bf16(af[i], bfr[j], acc[i][j], 0, 0, 0);
    }
    __builtin_amdgcn_s_setprio(0);
    // all frag ds_reads retired (data consumed by MFMAs above); next-buf loads done:
    asm volatile("s_waitcnt vmcnt(0) lgkmcnt(0)" ::: "memory");
    __builtin_amdgcn_sched_barrier(0);
    __builtin_amdgcn_s_barrier();
    __builtin_amdgcn_sched_barrier(0);
    cur ^= 1;
  }

  float biasj[4]; int ncj[4];
  #pragma unroll
  for (int j = 0; j < 4; ++j) {
    int nc = n0 + wn * 64 + j * 16 + r16;
    ncj[j] = nc;
    biasj[j] = (nc < NOFF) ? ((nc < COFF) ? boff1[nc] : boff2[nc - COFF]) : 0.f;
  }
  #pragma unroll
  for (int i = 0; i < 4; ++i) {
    int mrow = m0 + wm * 64 + i * 16 + q * 4;
    int bb = mrow >> 13, p = mrow & (DHW - 1);
    #pragma unroll
    for (int j = 0; j < 4; ++j) {
      int nc = ncj[j];
      if (nc < NOFF) {
        int ch = (nc < COFF) ? nc : nc - COFF;
        size_t base = (nc < COFF) ? (size_t)OFF1_ELEM : (size_t)OFF2_ELEM;
        f32x4 v = acc[i][j] + biasj[j];
        *(f32x4*)(dout + base + ((size_t)(bb * COFF + ch)) * DHW + p) = v;
      }
    }
  }
}

// ---------------- fused deformable sampling + GEMM (+ BN partials) ----------------
// R5 structure unchanged; epilogue adds register-level BN partial reduction
// (sum/sumsq per channel per block) -> part[1024][128], replacing k_bnpart.
__global__ __launch_bounds__(256) void k_deform(
    const u16* __restrict__ src, const float* __restrict__ offs,
    const u16* __restrict__ wB, float* __restrict__ cdst,
    const u16* __restrict__ zpg, float* __restrict__ part)
{
  __shared__ u16 Al[2 * 16 * 64];   // 4KB  [tapHalf][pos][64ch], XOR-swizzled chunks
  __shared__ u16 Bl[2 * 64 * 64];   // 16KB [tapHalf][outch][64k], XOR-swizzled chunks
  const int tid = threadIdx.x;
  const int wv = tid >> 6, lane = tid & 63;
  const int mrow0 = blockIdx.x * 16;
  const int b  = mrow0 >> 13;
  const int p0 = mrow0 & (DHW - 1);

  // sampling role: th = tap-half (tid>>7), pos = (tid>>3)&15, group = tid&7
  const int th = tid >> 7;
  const int pl = (tid >> 3) & 15;
  const int g  = tid & 7;
  const int p  = p0 + pl;
  const int d = p >> 10, h = (p >> 5) & 31, w = p & 31;
  const u16* sb = src + (size_t)b * DHW * CC + g * 8;
  const size_t obase = ((size_t)(b * COFF + g * 81)) * DHW + p;
  u16* awp = &Al[th * 1024 + pl * 64 + ((g ^ (pl & 7)) << 3)];

  // B staging role: 4 gld16/thread covering 2 taps x 64 rows x 8 chunks
  const int lr = lane >> 3, lc = lane & 7;
  const int lcs = (lc ^ lr) << 3;   // row&7 == lr for all staged rows

  f32x4 acc = {};
  const int r16 = lane & 15, q = lane >> 4;
  const int rs = r16 & 7;

  for (int ph = 0; ph < 14; ++ph) {
    // ---- stage B tiles for taps 2ph, 2ph+1 ----
    #pragma unroll
    for (int i = 0; i < 4; ++i) {
      int tb = 2 * ph + (i >> 1);
      int row = (i & 1) * 32 + wv * 8 + lr;
      const u16* s = (tb < 27) ? (wB + (size_t)row * KTOT + tb * 64 + lcs) : zpg;
      gld16(s, &Bl[(i >> 1) * 4096 + (((i & 1) * 32 + wv * 8) * 64)]);
    }
    // ---- sample A for tap t = 2ph + th ----
    {
      int t = 2 * ph + th;
      float a8[8] = {0.f,0.f,0.f,0.f,0.f,0.f,0.f,0.f};
      if (t < 27) {
        int kd = t / 9 - 1, kh = (t / 3) % 3 - 1, kw = t % 3 - 1;
        size_t ob = obase + (size_t)(t * 3) * DHW;
        float pd = (float)(d + kd) + offs[ob];
        float phh = (float)(h + kh) + offs[ob + DHW];
        float pw = (float)(w + kw) + offs[ob + 2 * DHW];
        float fd0 = floorf(pd), fh0 = floorf(phh), fw0 = floorf(pw);
        float fd = pd - fd0, fh = phh - fh0, fw = pw - fw0;
        int d0 = (int)fd0, h0 = (int)fh0, w0 = (int)fw0;
        #pragma unroll
        for (int dd = 0; dd < 2; ++dd) {
          float wd = dd ? fd : 1.f - fd;
          int di = d0 + dd;
          #pragma unroll
          for (int hh = 0; hh < 2; ++hh) {
            float wh = hh ? fh : 1.f - fh;
            int hi = h0 + hh;
            #pragma unroll
            for (int ww = 0; ww < 2; ++ww) {
              int wi = w0 + ww;
              if (((unsigned)di < DDD) && ((unsigned)hi < HHH) && ((unsigned)wi < WWW)) {
                float wgt = wd * wh * (ww ? fw : 1.f - fw);
                bf16x8 v = *(const bf16x8*)(sb + (size_t)((di << 10) + (hi << 5) + wi) * CC);
                #pragma unroll
                for (int c = 0; c < 8; ++c) a8[c] += wgt * bf2f((u16)v[c]);
              }
            }
          }
        }
      }
      union { bf16x8 v; u16 u[8]; } o;
      #pragma unroll
      for (int c = 0; c < 8; ++c) o.u[c] = f2bf(a8[c]);
      *(bf16x8*)awp = o.v;
    }
    __syncthreads();
    // ---- MFMA: K=128 (2 taps x 64); wave wv = outch 16-tile ----
    #pragma unroll
    for (int tt = 0; tt < 2; ++tt) {
      #pragma unroll
      for (int kk = 0; kk < 2; ++kk) {
        const int cs = ((kk * 4 + q) ^ rs) << 3;
        bf16x8 af = *(const bf16x8*)&Al[tt * 1024 + r16 * 64 + cs];
        bf16x8 bf_ = *(const bf16x8*)&Bl[tt * 4096 + (wv * 16 + r16) * 64 + cs];
        acc = __builtin_amdgcn_mfma_f32_16x16x32_bf16(af, bf_, acc, 0, 0, 0);
      }
    }
    __syncthreads();
  }

  {
    int nc = wv * 16 + r16;
    int mr = mrow0 + q * 4;
    #pragma unroll
    for (int r = 0; r < 4; ++r)
      cdst[(size_t)(mr + r) * CC + nc] = acc[r];
  }

  // ---- BN partials from registers: sum over the block's 16 rows per channel ----
  {
    float s  = acc[0] + acc[1] + acc[2] + acc[3];
    float s2 = acc[0]*acc[0] + acc[1]*acc[1] + acc[2]*acc[2] + acc[3]*acc[3];
    s  += __shfl_down(s, 16, 64);  s  += __shfl_down(s, 32, 64);
    s2 += __shfl_down(s2, 16, 64); s2 += __shfl_down(s2, 32, 64);
    if (lane < 16) {
      part[(size_t)blockIdx.x * 128 + wv * 16 + lane] = s;
      part[(size_t)blockIdx.x * 128 + 64 + wv * 16 + lane] = s2;
    }
  }
}

// ---------------- batchnorm finalize (reduces 1024 block-partials) ----------------
__global__ void k_bnfin(const float* __restrict__ part, const float* __restrict__ gamma,
                        const float* __restrict__ beta, float* __restrict__ stats)
{
  int tid = threadIdx.x;  // 0..127
  float S = 0.f;
  #pragma unroll 8
  for (int k = 0; k < 1024; ++k) S += part[(size_t)k * 128 + tid];
  __shared__ float sh[128];
  sh[tid] = S;
  __syncthreads();
  if (tid < 64) {
    float mu = sh[tid] / (float)MTOT;
    float var = sh[64 + tid] / (float)MTOT - mu * mu;
    float sc = gamma[tid] / sqrtf(var + 1e-5f);
    stats[tid] = sc;
    stats[64 + tid] = beta[tid] - mu * sc;
  }
}

__global__ void k_apply1(const float* __restrict__ c1, const float* __restrict__ st,
                         u16* __restrict__ ycl)
{
  int idx = blockIdx.x * 256 + threadIdx.x;  // over 16384*64
  if (idx >= MTOT * CC) return;
  int n = idx & 63;
  float v = st[n] * c1[idx] + st[64 + n];
  ycl[idx] = f2bf(fmaxf(v, 0.f));
}

__global__ void k_apply2(const float* __restrict__ c2, const float* __restrict__ st,
                         const float* __restrict__ x, float* __restrict__ out)
{
  int idx = blockIdx.x * 256 + threadIdx.x;  // NCDHW flat, 2^20
  if (idx >= BB * CC * DHW) return;
  int p = idx & (DHW - 1);
  int n = (idx >> 13) & 63;
  int b = idx >> 19;
  float v = st[n] * c2[(size_t)(b * DHW + p) * CC + n] + st[64 + n] + x[idx];
  out[idx] = fmaxf(v, 0.f);
}

// ---------------- host ----------------
extern "C" void kernel_launch(void* const* d_in, const int* in_sizes, int n_in,
                              void* d_out, int out_size, void* d_ws, size_t ws_size,
                              hipStream_t stream)
{
  (void)in_sizes; (void)n_in; (void)out_size; (void)ws_size;
  const float* x      = (const float*)d_in[0];
  const float* w_off1 = (const float*)d_in[1];
  const float* b_off1 = (const float*)d_in[2];
  const float* w1     = (const float*)d_in[3];
  const float* g1     = (const float*)d_in[4];
  const float* be1    = (const float*)d_in[5];
  const float* w_off2 = (const float*)d_in[6];
  const float* b_off2 = (const float*)d_in[7];
  const float* w2     = (const float*)d_in[8];
  const float* g2     = (const float*)d_in[9];
  const float* be2    = (const float*)d_in[10];

  char* ws = (char*)d_ws;
  u16*   xcl  = (u16*)(ws + XCL_OFF);
  u16*   ycl  = (u16*)(ws + YCL_OFF);
  u16*   woff = (u16*)(ws + WOFF_OFF);
  u16*   w1b  = (u16*)(ws + W1_OFF);
  u16*   w2b  = (u16*)(ws + W2_OFF);
  float* c1   = (float*)(ws + C1_OFF);
  float* c2   = (float*)(ws + C2_OFF);
  float* st1  = (float*)(ws + ST1_OFF);
  float* st2  = (float*)(ws + ST2_OFF);
  u16*   zpg  = (u16*)(ws + ZPG_OFF);
  float* part = (float*)(ws + PART_OFF);
  float* out  = (float*)d_out;

  k_prep<<<(PRETOT + 255) / 256, 256, 0, stream>>>(
      x, w_off1, w_off2, w1, w2, xcl, woff, w1b, w2b, zpg);

  k_gemm_off<<<dim3(MTOT / 128, NOFFP / 128), 256, 0, stream>>>(
      xcl, woff, b_off1, b_off2, out, zpg);

  k_deform<<<MTOT / 16, 256, 0, stream>>>(xcl, out + OFF1_ELEM, w1b, c1, zpg, part);
  k_bnfin<<<1, 128, 0, stream>>>(part, g1, be1, st1);
  k_apply1<<<(MTOT * CC) / 256, 256, 0, stream>>>(c1, st1, ycl);

  k_deform<<<MTOT / 16, 256, 0, stream>>>(ycl, out + OFF2_ELEM, w2b, c2, zpg, part);
  k_bnfin<<<1, 128, 0, stream>>>(part, g2, be2, st2);
  k_apply2<<<(BB*CC*DHW) / 256, 256, 0, stream>>>(c2, st2, x, out);
}

// Round 8
// 242.326 us; speedup vs baseline: 1.3456x; 1.3456x over previous
//
#include <hip/hip_runtime.h>
#include <stdint.h>

typedef unsigned short u16;
typedef __attribute__((ext_vector_type(8))) short bf16x8;
typedef __attribute__((ext_vector_type(4))) float f32x4;

#define DEV static __device__ __forceinline__

// problem dims
#define BB    2
#define CC    64
#define DDD   8
#define HHH   32
#define WWW   32
#define DHW   8192
#define MTOT  16384
#define GG    8
#define KTOT  1728
#define NOFF  1296
#define NOFFP 1408
#define COFF  648

// d_out element offsets (out, off1, off2 concatenated)
#define OFF1_ELEM (BB*CC*DHW)                 // 1048576
#define OFF2_ELEM (OFF1_ELEM + BB*COFF*DHW)   // 11665408

// ws byte offsets (all 256-aligned)
#define XCL_OFF   0ull         // bf16 [16384][64] channels-last x
#define YCL_OFF   2097152ull   // bf16 [16384][64] channels-last relu(bn1)
#define WOFF_OFF  4194304ull   // bf16 [1408][1728] off weights (k = tap*64+cin)
#define W1_OFF    9060352ull   // bf16 [64][1728]
#define W2_OFF    9281536ull
#define C1_OFF    9502720ull   // f32 [16384][64] deform1 raw out (channels-last)
#define C2_OFF    13697024ull
#define ST1_OFF   17891328ull  // f32 scale[64], shift[64]
#define ST2_OFF   17891840ull
#define ZPG_OFF   17892352ull  // 256B zeros (OOB source for global_load_lds)
#define PART_OFF  17892608ull  // f32 [1024][128] bn partials (from k_deform)
#define PART2_OFF 18416896ull  // f32 [64][128] stage-2 partials

DEV float bf2f(u16 u){ union { uint32_t i; float f; } v; v.i = ((uint32_t)u) << 16; return v.f; }
DEV u16 f2bf(float f){ union { float f; uint32_t i; } v; v.f = f;
  uint32_t r = v.i + 0x7fffu + ((v.i >> 16) & 1u); return (u16)(r >> 16); }

DEV void gld16(const void* g, void* l){
  __builtin_amdgcn_global_load_lds((const __attribute__((address_space(1))) void*)g,
                                   (__attribute__((address_space(3))) void*)l, 16, 0, 0);
}

// ---------------- merged prep ----------------
#define PRE0 (BB*CC*DHW)            // xcl
#define PRE1 (PRE0 + NOFFP*KTOT)    // woff
#define PRE2 (PRE1 + CC*KTOT)       // w1b
#define PRE3 (PRE2 + CC*KTOT)       // w2b
#define PRETOT (PRE3 + 128)         // zpg (128 u16)

__global__ void k_prep(const float* __restrict__ x,
                       const float* __restrict__ wo1, const float* __restrict__ wo2,
                       const float* __restrict__ w1, const float* __restrict__ w2,
                       u16* __restrict__ xcl, u16* __restrict__ woff,
                       u16* __restrict__ w1b, u16* __restrict__ w2b,
                       u16* __restrict__ zpg)
{
  int idx = blockIdx.x * 256 + threadIdx.x;
  if (idx < PRE0) {
    int p = idx & (DHW - 1);
    int c = (idx >> 13) & 63;
    int b = idx >> 19;
    xcl[(size_t)(b * DHW + p) * CC + c] = f2bf(x[idx]);
  } else if (idx < PRE1) {
    int j = idx - PRE0;
    int k = j % KTOT, n = j / KTOT;
    int tap = k >> 6, cin = k & 63;
    float v = 0.f;
    if (n < NOFF) {
      const float* w = (n < COFF) ? wo1 : wo2;
      int nn = (n < COFF) ? n : n - COFF;
      v = w[(size_t)nn * KTOT + cin * 27 + tap];
    }
    woff[j] = f2bf(v);
  } else if (idx < PRE2) {
    int j = idx - PRE1;
    int k = j % KTOT, n = j / KTOT;
    int tap = k >> 6, cin = k & 63;
    w1b[j] = f2bf(w1[(size_t)n * KTOT + cin * 27 + tap]);
  } else if (idx < PRE3) {
    int j = idx - PRE2;
    int k = j % KTOT, n = j / KTOT;
    int tap = k >> 6, cin = k & 63;
    w2b[j] = f2bf(w2[(size_t)n * KTOT + cin * 27 + tap]);
  } else if (idx < PRETOT) {
    zpg[idx - PRE3] = 0;
  }
}

// ---------------- offset conv GEMM (R1/R5-proven: implicit im2col, swizzled, single-buf) ----------------
// BM=BN=128, 256 threads. LDS[row][chunk] = global[row][chunk ^ (row&7)] (chunk=16B).
__global__ __launch_bounds__(256) void k_gemm_off(
    const u16* __restrict__ xcl, const u16* __restrict__ woff,
    const float* __restrict__ boff1, const float* __restrict__ boff2,
    float* __restrict__ dout, const u16* __restrict__ zpg)
{
  __shared__ u16 Al[128 * 64];
  __shared__ u16 Bl[128 * 64];
  const int tid = threadIdx.x;
  const int wv = tid >> 6, lane = tid & 63;
  const int m0 = blockIdx.x * 128;
  const int n0 = blockIdx.y * 128;
  const int lr = lane >> 3, lc = lane & 7;
  const int lcs = (lc ^ lr) << 3;      // swizzled source element offset within 128B row
  const int b  = m0 >> 13;
  const int p0 = m0 & (DHW - 1);
  int ad[4], ah[4], aw[4];
  #pragma unroll
  for (int i = 0; i < 4; ++i) {
    int p = p0 + wv * 32 + i * 8 + lr;
    ad[i] = p >> 10; ah[i] = (p >> 5) & 31; aw[i] = p & 31;
  }
  const size_t xb = (size_t)b * DHW * CC;

  f32x4 acc[4][4] = {};
  const int wm = wv >> 1, wn = wv & 1;
  const int r16 = lane & 15, q = lane >> 4;
  const int rs = r16 & 7;

  for (int t = 0; t < 27; ++t) {
    int kd = t / 9 - 1, kh = (t / 3) % 3 - 1, kw = t % 3 - 1;
    #pragma unroll
    for (int i = 0; i < 4; ++i) {
      int d2 = ad[i] + kd, h2 = ah[i] + kh, w2 = aw[i] + kw;
      bool ok = ((unsigned)d2 < DDD) & ((unsigned)h2 < HHH) & ((unsigned)w2 < WWW);
      const u16* src = ok ? (xcl + xb + (size_t)((d2 << 10) + (h2 << 5) + w2) * CC + lcs)
                          : zpg;
      gld16(src, &Al[(wv * 32 + i * 8) * 64]);
    }
    #pragma unroll
    for (int i = 0; i < 4; ++i) {
      int r = wv * 32 + i * 8 + lr;
      const u16* src = woff + (size_t)(n0 + r) * KTOT + t * 64 + lcs;
      gld16(src, &Bl[(wv * 32 + i * 8) * 64]);
    }
    __syncthreads();
    #pragma unroll
    for (int kk = 0; kk < 2; ++kk) {
      const int cs = ((kk * 4 + q) ^ rs) << 3;   // swizzled read chunk
      bf16x8 af[4], bfr[4];
      #pragma unroll
      for (int i = 0; i < 4; ++i)
        af[i] = *(const bf16x8*)&Al[(wm * 64 + i * 16 + r16) * 64 + cs];
      #pragma unroll
      for (int j = 0; j < 4; ++j)
        bfr[j] = *(const bf16x8*)&Bl[(wn * 64 + j * 16 + r16) * 64 + cs];
      #pragma unroll
      for (int i = 0; i < 4; ++i)
        #pragma unroll
        for (int j = 0; j < 4; ++j)
          acc[i][j] = __builtin_amdgcn_mfma_f32_16x16x32_bf16(af[i], bfr[j], acc[i][j], 0, 0, 0);
    }
    __syncthreads();
  }

  float biasj[4]; int ncj[4];
  #pragma unroll
  for (int j = 0; j < 4; ++j) {
    int nc = n0 + wn * 64 + j * 16 + r16;
    ncj[j] = nc;
    biasj[j] = (nc < NOFF) ? ((nc < COFF) ? boff1[nc] : boff2[nc - COFF]) : 0.f;
  }
  #pragma unroll
  for (int i = 0; i < 4; ++i) {
    int mrow = m0 + wm * 64 + i * 16 + q * 4;
    int bb = mrow >> 13, p = mrow & (DHW - 1);
    #pragma unroll
    for (int j = 0; j < 4; ++j) {
      int nc = ncj[j];
      if (nc < NOFF) {
        int ch = (nc < COFF) ? nc : nc - COFF;
        size_t base = (nc < COFF) ? (size_t)OFF1_ELEM : (size_t)OFF2_ELEM;
        f32x4 v = acc[i][j] + biasj[j];
        *(f32x4*)(dout + base + ((size_t)(bb * COFF + ch)) * DHW + p) = v;
      }
    }
  }
}

// ---------------- fused deformable sampling + GEMM (+ BN partials) ----------------
// R5 structure; epilogue adds register-level BN partial reduction -> part[1024][128].
__global__ __launch_bounds__(256) void k_deform(
    const u16* __restrict__ src, const float* __restrict__ offs,
    const u16* __restrict__ wB, float* __restrict__ cdst,
    const u16* __restrict__ zpg, float* __restrict__ part)
{
  __shared__ u16 Al[2 * 16 * 64];   // 4KB  [tapHalf][pos][64ch], XOR-swizzled chunks
  __shared__ u16 Bl[2 * 64 * 64];   // 16KB [tapHalf][outch][64k], XOR-swizzled chunks
  const int tid = threadIdx.x;
  const int wv = tid >> 6, lane = tid & 63;
  const int mrow0 = blockIdx.x * 16;
  const int b  = mrow0 >> 13;
  const int p0 = mrow0 & (DHW - 1);

  // sampling role: th = tap-half (tid>>7), pos = (tid>>3)&15, group = tid&7
  const int th = tid >> 7;
  const int pl = (tid >> 3) & 15;
  const int g  = tid & 7;
  const int p  = p0 + pl;
  const int d = p >> 10, h = (p >> 5) & 31, w = p & 31;
  const u16* sb = src + (size_t)b * DHW * CC + g * 8;
  const size_t obase = ((size_t)(b * COFF + g * 81)) * DHW + p;
  u16* awp = &Al[th * 1024 + pl * 64 + ((g ^ (pl & 7)) << 3)];

  // B staging role: 4 gld16/thread covering 2 taps x 64 rows x 8 chunks
  const int lr = lane >> 3, lc = lane & 7;
  const int lcs = (lc ^ lr) << 3;   // row&7 == lr for all staged rows

  f32x4 acc = {};
  const int r16 = lane & 15, q = lane >> 4;
  const int rs = r16 & 7;

  for (int ph = 0; ph < 14; ++ph) {
    // ---- stage B tiles for taps 2ph, 2ph+1 ----
    #pragma unroll
    for (int i = 0; i < 4; ++i) {
      int tb = 2 * ph + (i >> 1);
      int row = (i & 1) * 32 + wv * 8 + lr;
      const u16* s = (tb < 27) ? (wB + (size_t)row * KTOT + tb * 64 + lcs) : zpg;
      gld16(s, &Bl[(i >> 1) * 4096 + (((i & 1) * 32 + wv * 8) * 64)]);
    }
    // ---- sample A for tap t = 2ph + th ----
    {
      int t = 2 * ph + th;
      float a8[8] = {0.f,0.f,0.f,0.f,0.f,0.f,0.f,0.f};
      if (t < 27) {
        int kd = t / 9 - 1, kh = (t / 3) % 3 - 1, kw = t % 3 - 1;
        size_t ob = obase + (size_t)(t * 3) * DHW;
        float pd = (float)(d + kd) + offs[ob];
        float phh = (float)(h + kh) + offs[ob + DHW];
        float pw = (float)(w + kw) + offs[ob + 2 * DHW];
        float fd0 = floorf(pd), fh0 = floorf(phh), fw0 = floorf(pw);
        float fd = pd - fd0, fh = phh - fh0, fw = pw - fw0;
        int d0 = (int)fd0, h0 = (int)fh0, w0 = (int)fw0;
        #pragma unroll
        for (int dd = 0; dd < 2; ++dd) {
          float wd = dd ? fd : 1.f - fd;
          int di = d0 + dd;
          #pragma unroll
          for (int hh = 0; hh < 2; ++hh) {
            float wh = hh ? fh : 1.f - fh;
            int hi = h0 + hh;
            #pragma unroll
            for (int ww = 0; ww < 2; ++ww) {
              int wi = w0 + ww;
              if (((unsigned)di < DDD) && ((unsigned)hi < HHH) && ((unsigned)wi < WWW)) {
                float wgt = wd * wh * (ww ? fw : 1.f - fw);
                bf16x8 v = *(const bf16x8*)(sb + (size_t)((di << 10) + (hi << 5) + wi) * CC);
                #pragma unroll
                for (int c = 0; c < 8; ++c) a8[c] += wgt * bf2f((u16)v[c]);
              }
            }
          }
        }
      }
      union { bf16x8 v; u16 u[8]; } o;
      #pragma unroll
      for (int c = 0; c < 8; ++c) o.u[c] = f2bf(a8[c]);
      *(bf16x8*)awp = o.v;
    }
    __syncthreads();
    // ---- MFMA: K=128 (2 taps x 64); wave wv = outch 16-tile ----
    #pragma unroll
    for (int tt = 0; tt < 2; ++tt) {
      #pragma unroll
      for (int kk = 0; kk < 2; ++kk) {
        const int cs = ((kk * 4 + q) ^ rs) << 3;
        bf16x8 af = *(const bf16x8*)&Al[tt * 1024 + r16 * 64 + cs];
        bf16x8 bf_ = *(const bf16x8*)&Bl[tt * 4096 + (wv * 16 + r16) * 64 + cs];
        acc = __builtin_amdgcn_mfma_f32_16x16x32_bf16(af, bf_, acc, 0, 0, 0);
      }
    }
    __syncthreads();
  }

  {
    int nc = wv * 16 + r16;
    int mr = mrow0 + q * 4;
    #pragma unroll
    for (int r = 0; r < 4; ++r)
      cdst[(size_t)(mr + r) * CC + nc] = acc[r];
  }

  // ---- BN partials from registers: sum over this block's 16 rows per channel ----
  {
    float s  = acc[0] + acc[1] + acc[2] + acc[3];
    float s2 = acc[0]*acc[0] + acc[1]*acc[1] + acc[2]*acc[2] + acc[3]*acc[3];
    s  += __shfl_down(s, 16, 64);  s  += __shfl_down(s, 32, 64);
    s2 += __shfl_down(s2, 16, 64); s2 += __shfl_down(s2, 32, 64);
    if (lane < 16) {
      part[(size_t)blockIdx.x * 128 + wv * 16 + lane] = s;
      part[(size_t)blockIdx.x * 128 + 64 + wv * 16 + lane] = s2;
    }
  }
}

// ---------------- batchnorm reduce tree ----------------
// stage 1: 64 blocks x 128 thr; block k sums part rows k*16..k*16+15 -> part2[k][128]
__global__ void k_bnred(const float* __restrict__ part, float* __restrict__ part2)
{
  int k = blockIdx.x, tid = threadIdx.x;   // tid 0..127
  float s = 0.f;
  #pragma unroll
  for (int j = 0; j < 16; ++j)
    s += part[(size_t)(k * 16 + j) * 128 + tid];
  part2[(size_t)k * 128 + tid] = s;
}

// stage 2: 1 block x 128 thr; 64-iter loop
__global__ void k_bnfin(const float* __restrict__ part2, const float* __restrict__ gamma,
                        const float* __restrict__ beta, float* __restrict__ stats)
{
  int tid = threadIdx.x;  // 0..127
  float S = 0.f;
  #pragma unroll 8
  for (int k = 0; k < 64; ++k) S += part2[(size_t)k * 128 + tid];
  __shared__ float sh[128];
  sh[tid] = S;
  __syncthreads();
  if (tid < 64) {
    float mu = sh[tid] / (float)MTOT;
    float var = sh[64 + tid] / (float)MTOT - mu * mu;
    float sc = gamma[tid] / sqrtf(var + 1e-5f);
    stats[tid] = sc;
    stats[64 + tid] = beta[tid] - mu * sc;
  }
}

__global__ void k_apply1(const float* __restrict__ c1, const float* __restrict__ st,
                         u16* __restrict__ ycl)
{
  int idx = blockIdx.x * 256 + threadIdx.x;  // over 16384*64
  if (idx >= MTOT * CC) return;
  int n = idx & 63;
  float v = st[n] * c1[idx] + st[64 + n];
  ycl[idx] = f2bf(fmaxf(v, 0.f));
}

__global__ void k_apply2(const float* __restrict__ c2, const float* __restrict__ st,
                         const float* __restrict__ x, float* __restrict__ out)
{
  int idx = blockIdx.x * 256 + threadIdx.x;  // NCDHW flat, 2^20
  if (idx >= BB * CC * DHW) return;
  int p = idx & (DHW - 1);
  int n = (idx >> 13) & 63;
  int b = idx >> 19;
  float v = st[n] * c2[(size_t)(b * DHW + p) * CC + n] + st[64 + n] + x[idx];
  out[idx] = fmaxf(v, 0.f);
}

// ---------------- host ----------------
extern "C" void kernel_launch(void* const* d_in, const int* in_sizes, int n_in,
                              void* d_out, int out_size, void* d_ws, size_t ws_size,
                              hipStream_t stream)
{
  (void)in_sizes; (void)n_in; (void)out_size; (void)ws_size;
  const float* x      = (const float*)d_in[0];
  const float* w_off1 = (const float*)d_in[1];
  const float* b_off1 = (const float*)d_in[2];
  const float* w1     = (const float*)d_in[3];
  const float* g1     = (const float*)d_in[4];
  const float* be1    = (const float*)d_in[5];
  const float* w_off2 = (const float*)d_in[6];
  const float* b_off2 = (const float*)d_in[7];
  const float* w2     = (const float*)d_in[8];
  const float* g2     = (const float*)d_in[9];
  const float* be2    = (const float*)d_in[10];

  char* ws = (char*)d_ws;
  u16*   xcl   = (u16*)(ws + XCL_OFF);
  u16*   ycl   = (u16*)(ws + YCL_OFF);
  u16*   woff  = (u16*)(ws + WOFF_OFF);
  u16*   w1b   = (u16*)(ws + W1_OFF);
  u16*   w2b   = (u16*)(ws + W2_OFF);
  float* c1    = (float*)(ws + C1_OFF);
  float* c2    = (float*)(ws + C2_OFF);
  float* st1   = (float*)(ws + ST1_OFF);
  float* st2   = (float*)(ws + ST2_OFF);
  u16*   zpg   = (u16*)(ws + ZPG_OFF);
  float* part  = (float*)(ws + PART_OFF);
  float* part2 = (float*)(ws + PART2_OFF);
  float* out   = (float*)d_out;

  k_prep<<<(PRETOT + 255) / 256, 256, 0, stream>>>(
      x, w_off1, w_off2, w1, w2, xcl, woff, w1b, w2b, zpg);

  k_gemm_off<<<dim3(MTOT / 128, NOFFP / 128), 256, 0, stream>>>(
      xcl, woff, b_off1, b_off2, out, zpg);

  k_deform<<<MTOT / 16, 256, 0, stream>>>(xcl, out + OFF1_ELEM, w1b, c1, zpg, part);
  k_bnred<<<64, 128, 0, stream>>>(part, part2);
  k_bnfin<<<1, 128, 0, stream>>>(part2, g1, be1, st1);
  k_apply1<<<(MTOT * CC) / 256, 256, 0, stream>>>(c1, st1, ycl);

  k_deform<<<MTOT / 16, 256, 0, stream>>>(ycl, out + OFF2_ELEM, w2b, c2, zpg, part);
  k_bnred<<<64, 128, 0, stream>>>(part, part2);
  k_bnfin<<<1, 128, 0, stream>>>(part2, g2, be2, st2);
  k_apply2<<<(BB*CC*DHW) / 256, 256, 0, stream>>>(c2, st2, x, out);
}

// Round 9
// 238.615 us; speedup vs baseline: 1.3665x; 1.0156x over previous
//
#include <hip/hip_runtime.h>
#include <stdint.h>

typedef unsigned short u16;
typedef __attribute__((ext_vector_type(8))) short bf16x8;
typedef __attribute__((ext_vector_type(4))) float f32x4;

#define DEV static __device__ __forceinline__

// problem dims
#define BB    2
#define CC    64
#define DDD   8
#define HHH   32
#define WWW   32
#define DHW   8192
#define MTOT  16384
#define GG    8
#define KTOT  1728
#define NOFF  1296
#define NOFFP 1408
#define COFF  648

// d_out element offsets (out, off1, off2 concatenated)
#define OFF1_ELEM (BB*CC*DHW)                 // 1048576
#define OFF2_ELEM (OFF1_ELEM + BB*COFF*DHW)   // 11665408

// ws byte offsets (all 256-aligned)
#define XCL_OFF   0ull         // bf16 [16384][64] channels-last x (gemm_off A source)
#define YCL_OFF   2097152ull   // (unused this round)
#define WOFF_OFF  4194304ull   // bf16 [1408][1728] off weights (k = tap*64+cin)
#define W1_OFF    9060352ull   // bf16 [64][1728]
#define W2_OFF    9281536ull
#define C1_OFF    9502720ull   // f32 [16384][64] deform1 raw out (channels-last)
#define C2_OFF    13697024ull
#define ST1_OFF   17891328ull  // f32 scale[64], shift[64]
#define ST2_OFF   17891840ull
#define ZPG_OFF   17892352ull  // 256B zeros (OOB source for global_load_lds)
#define PART_OFF  17892608ull  // f32 [1024][128] bn partials (from k_deform)
#define PART2_OFF 18416896ull  // f32 [64][128] stage-2 partials
#define XCL2_OFF  18449664ull  // bf16 [2][8][8192][8] group-major x (deform gather source)
#define YCL2_OFF  20546816ull  // bf16 [2][8][8192][8] group-major relu(bn1)

DEV float bf2f(u16 u){ union { uint32_t i; float f; } v; v.i = ((uint32_t)u) << 16; return v.f; }
DEV u16 f2bf(float f){ union { float f; uint32_t i; } v; v.f = f;
  uint32_t r = v.i + 0x7fffu + ((v.i >> 16) & 1u); return (u16)(r >> 16); }

DEV void gld16(const void* g, void* l){
  __builtin_amdgcn_global_load_lds((const __attribute__((address_space(1))) void*)g,
                                   (__attribute__((address_space(3))) void*)l, 16, 0, 0);
}

// ---------------- merged prep ----------------
#define PRE0 (BB*CC*DHW)            // xcl + xcl2
#define PRE1 (PRE0 + NOFFP*KTOT)    // woff
#define PRE2 (PRE1 + CC*KTOT)       // w1b
#define PRE3 (PRE2 + CC*KTOT)       // w2b
#define PRETOT (PRE3 + 128)         // zpg (128 u16)

__global__ void k_prep(const float* __restrict__ x,
                       const float* __restrict__ wo1, const float* __restrict__ wo2,
                       const float* __restrict__ w1, const float* __restrict__ w2,
                       u16* __restrict__ xcl, u16* __restrict__ xcl2,
                       u16* __restrict__ woff,
                       u16* __restrict__ w1b, u16* __restrict__ w2b,
                       u16* __restrict__ zpg)
{
  int idx = blockIdx.x * 256 + threadIdx.x;
  if (idx < PRE0) {
    int p = idx & (DHW - 1);
    int c = (idx >> 13) & 63;
    int b = idx >> 19;
    u16 v = f2bf(x[idx]);
    xcl[(size_t)(b * DHW + p) * CC + c] = v;
    // group-major copy: [b][g][p][8]
    int g = c >> 3, cc = c & 7;
    xcl2[(((size_t)(b * GG + g)) * DHW + p) * 8 + cc] = v;
  } else if (idx < PRE1) {
    int j = idx - PRE0;
    int k = j % KTOT, n = j / KTOT;
    int tap = k >> 6, cin = k & 63;
    float v = 0.f;
    if (n < NOFF) {
      const float* w = (n < COFF) ? wo1 : wo2;
      int nn = (n < COFF) ? n : n - COFF;
      v = w[(size_t)nn * KTOT + cin * 27 + tap];
    }
    woff[j] = f2bf(v);
  } else if (idx < PRE2) {
    int j = idx - PRE1;
    int k = j % KTOT, n = j / KTOT;
    int tap = k >> 6, cin = k & 63;
    w1b[j] = f2bf(w1[(size_t)n * KTOT + cin * 27 + tap]);
  } else if (idx < PRE3) {
    int j = idx - PRE2;
    int k = j % KTOT, n = j / KTOT;
    int tap = k >> 6, cin = k & 63;
    w2b[j] = f2bf(w2[(size_t)n * KTOT + cin * 27 + tap]);
  } else if (idx < PRETOT) {
    zpg[idx - PRE3] = 0;
  }
}

// ---------------- offset conv GEMM (R1/R5-proven: implicit im2col, swizzled, single-buf) ----------------
// BM=BN=128, 256 threads. LDS[row][chunk] = global[row][chunk ^ (row&7)] (chunk=16B).
__global__ __launch_bounds__(256) void k_gemm_off(
    const u16* __restrict__ xcl, const u16* __restrict__ woff,
    const float* __restrict__ boff1, const float* __restrict__ boff2,
    float* __restrict__ dout, const u16* __restrict__ zpg)
{
  __shared__ u16 Al[128 * 64];
  __shared__ u16 Bl[128 * 64];
  const int tid = threadIdx.x;
  const int wv = tid >> 6, lane = tid & 63;
  const int m0 = blockIdx.x * 128;
  const int n0 = blockIdx.y * 128;
  const int lr = lane >> 3, lc = lane & 7;
  const int lcs = (lc ^ lr) << 3;      // swizzled source element offset within 128B row
  const int b  = m0 >> 13;
  const int p0 = m0 & (DHW - 1);
  int ad[4], ah[4], aw[4];
  #pragma unroll
  for (int i = 0; i < 4; ++i) {
    int p = p0 + wv * 32 + i * 8 + lr;
    ad[i] = p >> 10; ah[i] = (p >> 5) & 31; aw[i] = p & 31;
  }
  const size_t xb = (size_t)b * DHW * CC;

  f32x4 acc[4][4] = {};
  const int wm = wv >> 1, wn = wv & 1;
  const int r16 = lane & 15, q = lane >> 4;
  const int rs = r16 & 7;

  for (int t = 0; t < 27; ++t) {
    int kd = t / 9 - 1, kh = (t / 3) % 3 - 1, kw = t % 3 - 1;
    #pragma unroll
    for (int i = 0; i < 4; ++i) {
      int d2 = ad[i] + kd, h2 = ah[i] + kh, w2 = aw[i] + kw;
      bool ok = ((unsigned)d2 < DDD) & ((unsigned)h2 < HHH) & ((unsigned)w2 < WWW);
      const u16* src = ok ? (xcl + xb + (size_t)((d2 << 10) + (h2 << 5) + w2) * CC + lcs)
                          : zpg;
      gld16(src, &Al[(wv * 32 + i * 8) * 64]);
    }
    #pragma unroll
    for (int i = 0; i < 4; ++i) {
      int r = wv * 32 + i * 8 + lr;
      const u16* src = woff + (size_t)(n0 + r) * KTOT + t * 64 + lcs;
      gld16(src, &Bl[(wv * 32 + i * 8) * 64]);
    }
    __syncthreads();
    #pragma unroll
    for (int kk = 0; kk < 2; ++kk) {
      const int cs = ((kk * 4 + q) ^ rs) << 3;   // swizzled read chunk
      bf16x8 af[4], bfr[4];
      #pragma unroll
      for (int i = 0; i < 4; ++i)
        af[i] = *(const bf16x8*)&Al[(wm * 64 + i * 16 + r16) * 64 + cs];
      #pragma unroll
      for (int j = 0; j < 4; ++j)
        bfr[j] = *(const bf16x8*)&Bl[(wn * 64 + j * 16 + r16) * 64 + cs];
      #pragma unroll
      for (int i = 0; i < 4; ++i)
        #pragma unroll
        for (int j = 0; j < 4; ++j)
          acc[i][j] = __builtin_amdgcn_mfma_f32_16x16x32_bf16(af[i], bfr[j], acc[i][j], 0, 0, 0);
    }
    __syncthreads();
  }

  float biasj[4]; int ncj[4];
  #pragma unroll
  for (int j = 0; j < 4; ++j) {
    int nc = n0 + wn * 64 + j * 16 + r16;
    ncj[j] = nc;
    biasj[j] = (nc < NOFF) ? ((nc < COFF) ? boff1[nc] : boff2[nc - COFF]) : 0.f;
  }
  #pragma unroll
  for (int i = 0; i < 4; ++i) {
    int mrow = m0 + wm * 64 + i * 16 + q * 4;
    int bb = mrow >> 13, p = mrow & (DHW - 1);
    #pragma unroll
    for (int j = 0; j < 4; ++j) {
      int nc = ncj[j];
      if (nc < NOFF) {
        int ch = (nc < COFF) ? nc : nc - COFF;
        size_t base = (nc < COFF) ? (size_t)OFF1_ELEM : (size_t)OFF2_ELEM;
        f32x4 v = acc[i][j] + biasj[j];
        *(f32x4*)(dout + base + ((size_t)(bb * COFF + ch)) * DHW + p) = v;
      }
    }
  }
}

// ---------------- fused deformable sampling + GEMM (+ BN partials) ----------------
// Gather source is GROUP-MAJOR src2[b][g][dhw][8ch]: w-corners 16B apart (same line),
// same-g consecutive-p lanes ~1.3 lines/corner -> ~2x fewer lines/instr than [p][64].
// lane mapping: g = lane>>3 (same-g lanes consecutive in p), pos = (lane&7) + 8*(wv&1).
__global__ __launch_bounds__(256) void k_deform(
    const u16* __restrict__ src2, const float* __restrict__ offs,
    const u16* __restrict__ wB, float* __restrict__ cdst,
    const u16* __restrict__ zpg, float* __restrict__ part)
{
  __shared__ u16 Al[2 * 16 * 64];   // 4KB  [tapHalf][pos][64ch], XOR-swizzled chunks
  __shared__ u16 Bl[2 * 64 * 64];   // 16KB [tapHalf][outch][64k], XOR-swizzled chunks
  const int tid = threadIdx.x;
  const int wv = tid >> 6, lane = tid & 63;
  const int mrow0 = blockIdx.x * 16;
  const int b  = mrow0 >> 13;
  const int p0 = mrow0 & (DHW - 1);

  // sampling role: th = tap-half (wv>>1), pos = (lane&7)+8*(wv&1), group = lane>>3
  const int th = wv >> 1;
  const int pl = (lane & 7) + 8 * (wv & 1);
  const int g  = lane >> 3;
  const int p  = p0 + pl;
  const int d = p >> 10, h = (p >> 5) & 31, w = p & 31;
  const u16* sb = src2 + (((size_t)(b * GG + g)) * DHW) * 8;
  const size_t obase = ((size_t)(b * COFF + g * 81)) * DHW + p;
  u16* awp = &Al[th * 1024 + pl * 64 + ((g ^ (pl & 7)) << 3)];

  // B staging role: 4 gld16/thread covering 2 taps x 64 rows x 8 chunks
  const int lr = lane >> 3, lc = lane & 7;
  const int lcs = (lc ^ lr) << 3;   // row&7 == lr for all staged rows

  f32x4 acc = {};
  const int r16 = lane & 15, q = lane >> 4;
  const int rs = r16 & 7;

  for (int ph = 0; ph < 14; ++ph) {
    // ---- stage B tiles for taps 2ph, 2ph+1 ----
    #pragma unroll
    for (int i = 0; i < 4; ++i) {
      int tb = 2 * ph + (i >> 1);
      int row = (i & 1) * 32 + wv * 8 + lr;
      const u16* s = (tb < 27) ? (wB + (size_t)row * KTOT + tb * 64 + lcs) : zpg;
      gld16(s, &Bl[(i >> 1) * 4096 + (((i & 1) * 32 + wv * 8) * 64)]);
    }
    // ---- sample A for tap t = 2ph + th ----
    {
      int t = 2 * ph + th;
      float a8[8] = {0.f,0.f,0.f,0.f,0.f,0.f,0.f,0.f};
      if (t < 27) {
        int kd = t / 9 - 1, kh = (t / 3) % 3 - 1, kw = t % 3 - 1;
        size_t ob = obase + (size_t)(t * 3) * DHW;
        float pd = (float)(d + kd) + offs[ob];
        float phh = (float)(h + kh) + offs[ob + DHW];
        float pw = (float)(w + kw) + offs[ob + 2 * DHW];
        float fd0 = floorf(pd), fh0 = floorf(phh), fw0 = floorf(pw);
        float fd = pd - fd0, fh = phh - fh0, fw = pw - fw0;
        int d0 = (int)fd0, h0 = (int)fh0, w0 = (int)fw0;
        #pragma unroll
        for (int dd = 0; dd < 2; ++dd) {
          float wd = dd ? fd : 1.f - fd;
          int di = d0 + dd;
          #pragma unroll
          for (int hh = 0; hh < 2; ++hh) {
            float wh = hh ? fh : 1.f - fh;
            int hi = h0 + hh;
            const u16* rowb = sb + (size_t)((di << 10) + (hi << 5)) * 8;
            #pragma unroll
            for (int ww = 0; ww < 2; ++ww) {
              int wi = w0 + ww;
              if (((unsigned)di < DDD) && ((unsigned)hi < HHH) && ((unsigned)wi < WWW)) {
                float wgt = wd * wh * (ww ? fw : 1.f - fw);
                bf16x8 v = *(const bf16x8*)(rowb + (size_t)wi * 8);
                #pragma unroll
                for (int c = 0; c < 8; ++c) a8[c] += wgt * bf2f((u16)v[c]);
              }
            }
          }
        }
      }
      union { bf16x8 v; u16 u[8]; } o;
      #pragma unroll
      for (int c = 0; c < 8; ++c) o.u[c] = f2bf(a8[c]);
      *(bf16x8*)awp = o.v;
    }
    __syncthreads();
    // ---- MFMA: K=128 (2 taps x 64); wave wv = outch 16-tile ----
    #pragma unroll
    for (int tt = 0; tt < 2; ++tt) {
      #pragma unroll
      for (int kk = 0; kk < 2; ++kk) {
        const int cs = ((kk * 4 + q) ^ rs) << 3;
        bf16x8 af = *(const bf16x8*)&Al[tt * 1024 + r16 * 64 + cs];
        bf16x8 bf_ = *(const bf16x8*)&Bl[tt * 4096 + (wv * 16 + r16) * 64 + cs];
        acc = __builtin_amdgcn_mfma_f32_16x16x32_bf16(af, bf_, acc, 0, 0, 0);
      }
    }
    __syncthreads();
  }

  {
    int nc = wv * 16 + r16;
    int mr = mrow0 + q * 4;
    #pragma unroll
    for (int r = 0; r < 4; ++r)
      cdst[(size_t)(mr + r) * CC + nc] = acc[r];
  }

  // ---- BN partials from registers: sum over this block's 16 rows per channel ----
  {
    float s  = acc[0] + acc[1] + acc[2] + acc[3];
    float s2 = acc[0]*acc[0] + acc[1]*acc[1] + acc[2]*acc[2] + acc[3]*acc[3];
    s  += __shfl_down(s, 16, 64);  s  += __shfl_down(s, 32, 64);
    s2 += __shfl_down(s2, 16, 64); s2 += __shfl_down(s2, 32, 64);
    if (lane < 16) {
      part[(size_t)blockIdx.x * 128 + wv * 16 + lane] = s;
      part[(size_t)blockIdx.x * 128 + 64 + wv * 16 + lane] = s2;
    }
  }
}

// ---------------- batchnorm reduce tree ----------------
__global__ void k_bnred(const float* __restrict__ part, float* __restrict__ part2)
{
  int k = blockIdx.x, tid = threadIdx.x;   // 64 blocks x 128 thr
  float s = 0.f;
  #pragma unroll
  for (int j = 0; j < 16; ++j)
    s += part[(size_t)(k * 16 + j) * 128 + tid];
  part2[(size_t)k * 128 + tid] = s;
}

__global__ void k_bnfin(const float* __restrict__ part2, const float* __restrict__ gamma,
                        const float* __restrict__ beta, float* __restrict__ stats)
{
  int tid = threadIdx.x;  // 0..127
  float S = 0.f;
  #pragma unroll 8
  for (int k = 0; k < 64; ++k) S += part2[(size_t)k * 128 + tid];
  __shared__ float sh[128];
  sh[tid] = S;
  __syncthreads();
  if (tid < 64) {
    float mu = sh[tid] / (float)MTOT;
    float var = sh[64 + tid] / (float)MTOT - mu * mu;
    float sc = gamma[tid] / sqrtf(var + 1e-5f);
    stats[tid] = sc;
    stats[64 + tid] = beta[tid] - mu * sc;
  }
}

// apply BN1+relu, emit GROUP-MAJOR ycl2[b][g][p][8] for deform2's gather.
// thread -> (b, p, g): lanes 0..7 = g 0..7 of one p (full c1 row read, 2 lines).
__global__ void k_apply1(const float* __restrict__ c1, const float* __restrict__ st,
                         u16* __restrict__ ycl2)
{
  int idx = blockIdx.x * 256 + threadIdx.x;  // over B*DHW*G = 131072
  int g = idx & 7;
  int p = (idx >> 3) & (DHW - 1);
  int b = idx >> 16;
  const float* row = c1 + (size_t)(b * DHW + p) * CC + g * 8;
  union { bf16x8 v; u16 u[8]; } o;
  #pragma unroll
  for (int c = 0; c < 8; ++c) {
    int ch = g * 8 + c;
    float v = st[ch] * row[c] + st[64 + ch];
    o.u[c] = f2bf(fmaxf(v, 0.f));
  }
  *(bf16x8*)(ycl2 + ((((size_t)(b * GG + g)) * DHW + p) * 8)) = o.v;
}

__global__ void k_apply2(const float* __restrict__ c2, const float* __restrict__ st,
                         const float* __restrict__ x, float* __restrict__ out)
{
  int idx = blockIdx.x * 256 + threadIdx.x;  // NCDHW flat, 2^20
  if (idx >= BB * CC * DHW) return;
  int p = idx & (DHW - 1);
  int n = (idx >> 13) & 63;
  int b = idx >> 19;
  float v = st[n] * c2[(size_t)(b * DHW + p) * CC + n] + st[64 + n] + x[idx];
  out[idx] = fmaxf(v, 0.f);
}

// ---------------- host ----------------
extern "C" void kernel_launch(void* const* d_in, const int* in_sizes, int n_in,
                              void* d_out, int out_size, void* d_ws, size_t ws_size,
                              hipStream_t stream)
{
  (void)in_sizes; (void)n_in; (void)out_size; (void)ws_size;
  const float* x      = (const float*)d_in[0];
  const float* w_off1 = (const float*)d_in[1];
  const float* b_off1 = (const float*)d_in[2];
  const float* w1     = (const float*)d_in[3];
  const float* g1     = (const float*)d_in[4];
  const float* be1    = (const float*)d_in[5];
  const float* w_off2 = (const float*)d_in[6];
  const float* b_off2 = (const float*)d_in[7];
  const float* w2     = (const float*)d_in[8];
  const float* g2     = (const float*)d_in[9];
  const float* be2    = (const float*)d_in[10];

  char* ws = (char*)d_ws;
  u16*   xcl   = (u16*)(ws + XCL_OFF);
  u16*   xcl2  = (u16*)(ws + XCL2_OFF);
  u16*   ycl2  = (u16*)(ws + YCL2_OFF);
  u16*   woff  = (u16*)(ws + WOFF_OFF);
  u16*   w1b   = (u16*)(ws + W1_OFF);
  u16*   w2b   = (u16*)(ws + W2_OFF);
  float* c1    = (float*)(ws + C1_OFF);
  float* c2    = (float*)(ws + C2_OFF);
  float* st1   = (float*)(ws + ST1_OFF);
  float* st2   = (float*)(ws + ST2_OFF);
  u16*   zpg   = (u16*)(ws + ZPG_OFF);
  float* part  = (float*)(ws + PART_OFF);
  float* part2 = (float*)(ws + PART2_OFF);
  float* out   = (float*)d_out;

  k_prep<<<(PRETOT + 255) / 256, 256, 0, stream>>>(
      x, w_off1, w_off2, w1, w2, xcl, xcl2, woff, w1b, w2b, zpg);

  k_gemm_off<<<dim3(MTOT / 128, NOFFP / 128), 256, 0, stream>>>(
      xcl, woff, b_off1, b_off2, out, zpg);

  k_deform<<<MTOT / 16, 256, 0, stream>>>(xcl2, out + OFF1_ELEM, w1b, c1, zpg, part);
  k_bnred<<<64, 128, 0, stream>>>(part, part2);
  k_bnfin<<<1, 128, 0, stream>>>(part2, g1, be1, st1);
  k_apply1<<<(BB * DHW * GG) / 256, 256, 0, stream>>>(c1, st1, ycl2);

  k_deform<<<MTOT / 16, 256, 0, stream>>>(ycl2, out + OFF2_ELEM, w2b, c2, zpg, part);
  k_bnred<<<64, 128, 0, stream>>>(part, part2);
  k_bnfin<<<1, 128, 0, stream>>>(part2, g2, be2, st2);
  k_apply2<<<(BB*CC*DHW) / 256, 256, 0, stream>>>(c2, st2, x, out);
}